// Round 18
// baseline (44.277 us; speedup 1.0000x reference)
//
#include <hip/hip_runtime.h>

#define TPB 64
#define WPT 8                 // 16-row tiles per wave -> 128 rows/block
#define ROW_DW 20             // per-row LDS: xa[4] + h[16] dwords
#define NROWS (16 * WPT)      // 128
#define LDS_ROW_F32 (NROWS * ROW_DW)     // 2560
#define LDS_MU_F32 (NROWS * 3)           // 384
#define LOG2E 1.44269504088896340736f

typedef _Float16 half8 __attribute__((ext_vector_type(8)));
typedef __fp16  fp16x2 __attribute__((ext_vector_type(2)));
typedef float f32x4 __attribute__((ext_vector_type(4)));

__device__ __forceinline__ half8 pack8(float4 lo, float4 hi) {
    union { fp16x2 p[4]; half8 h; } u;
    u.p[0] = __builtin_amdgcn_cvt_pkrtz(lo.x, lo.y);
    u.p[1] = __builtin_amdgcn_cvt_pkrtz(lo.z, lo.w);
    u.p[2] = __builtin_amdgcn_cvt_pkrtz(hi.x, hi.y);
    u.p[3] = __builtin_amdgcn_cvt_pkrtz(hi.z, hi.w);
    return u.h;
}

__device__ __forceinline__ void nt_store4(float* p, float4 v) {
    union { float4 s; f32x4 e; } u;
    u.s = v;
    __builtin_nontemporal_store(u.e, (f32x4*)p);   // global_store_dwordx4 nt
}

// ---- ws layout ----
// halfs: 6 tiles x 512 halfs (r, z, n_i, n_h, hp-identity, A2) = 6144 B
// byte 6144: float4 bias[16] per gate col {b_r, b_z, b_ni, b_nh} = 256 B
// r,z tiles+biases pre-scaled by -log2(e); n_i,n_h by -2*log2(e): every
// sigmoid/tanh becomes bare v_exp_f32 (exp2) + v_rcp.
// A k-map: k0-3 = x(z0,z1,z2,act), k4-19 = h0..15, k20-31 = 0
// A2 rows m: 0-2 = W_mu, 3-5 = W_lv; k20 = bias slot (B2[20][n] = 1.0)

__global__ __launch_bounds__(64) void prep_kernel(
    const float* __restrict__ W_ih, const float* __restrict__ W_hh,
    const float* __restrict__ b_ih, const float* __restrict__ b_hh,
    const float* __restrict__ W_mu, const float* __restrict__ b_mu,
    const float* __restrict__ W_lv, const float* __restrict__ b_lv,
    void* __restrict__ wsv)
{
    _Float16* wsB = (_Float16*)wsv;
    const int l = threadIdx.x;
    const int col = l & 15, kg = l >> 4;

    #pragma unroll
    for (int t = 0; t < 4; ++t) {
        const int gate = (t == 0) ? col : (t == 1) ? (16 + col) : (32 + col);
        const float scale = (t <= 1) ? -LOG2E : -2.0f * LOG2E;
        #pragma unroll
        for (int i = 0; i < 8; ++i) {
            const int k = kg * 8 + i;
            float v = 0.f;
            if (t <= 1) {
                if (k < 4)       v = W_ih[gate * 4 + k];
                else if (k < 20) v = W_hh[gate * 16 + (k - 4)];
            } else if (t == 2) {
                if (k < 4)       v = W_ih[gate * 4 + k];
            } else {
                if (k >= 4 && k < 20) v = W_hh[gate * 16 + (k - 4)];
            }
            wsB[t * 512 + l * 8 + i] = (_Float16)(v * scale);
        }
    }
    // tile 4: hp identity  B[k][n] = (k == n+4)   (unscaled)
    #pragma unroll
    for (int i = 0; i < 8; ++i) {
        const int k = kg * 8 + i;
        wsB[4 * 512 + l * 8 + i] = (_Float16)((k == col + 4) ? 1.f : 0.f);
    }
    // tile 5: A2  lane holds A2[m = col][k = kg*8+i]   (unscaled)
    #pragma unroll
    for (int i = 0; i < 8; ++i) {
        const int k = kg * 8 + i;
        const int m = col;
        float v = 0.f;
        if (m < 3) {
            if (k < 16)       v = W_mu[m * 16 + k];
            else if (k == 20) v = b_mu[m];
        } else if (m < 6) {
            if (k < 16)       v = W_lv[(m - 3) * 16 + k];
            else if (k == 20) v = b_lv[m - 3];
        }
        wsB[5 * 512 + l * 8 + i] = (_Float16)v;
    }
    if (l < 16) {
        float4* b4 = (float4*)((char*)wsv + 6144);
        b4[l] = make_float4(-LOG2E * (b_ih[l] + b_hh[l]),
                            -LOG2E * (b_ih[16 + l] + b_hh[16 + l]),
                            -2.0f * LOG2E * b_ih[32 + l],
                            -2.0f * LOG2E * b_hh[32 + l]);
    }
}

template<bool EXACT>
__global__ __launch_bounds__(TPB, 4) void rssm_kernel(
    const float* __restrict__ prev_z,   // [B,3]
    const float* __restrict__ action,   // [B,1]
    const float* __restrict__ prev_h,   // [B,16]
    const void*  __restrict__ wsv,
    float* __restrict__ out_mu,         // [B,3]
    float* __restrict__ out_lv,         // [B,3]
    float* __restrict__ out_h,          // [B,16]
    int B)
{
    __shared__ float Wl[LDS_ROW_F32];
    __shared__ float MUl[LDS_MU_F32];
    __shared__ float LVl[LDS_MU_F32];
    const int lane = threadIdx.x;
    const int col = lane & 15, kg = lane >> 4;
    const int wbase = blockIdx.x * NROWS;
    if (!EXACT && wbase >= B) return;

    float* W  = Wl;
    float* MU = MUl;
    float* LV = LVl;

    // ---- wave-invariant fragments (once per 128 rows) ----
    const half8* Bp = (const half8*)wsv;
    const half8 bR  = Bp[lane];
    const half8 bZ  = Bp[64 + lane];
    const half8 bNi = Bp[128 + lane];
    const half8 bNh = Bp[192 + lane];
    const half8 bHp = Bp[256 + lane];
    const half8 a2  = Bp[320 + lane];
    const float4 bias = ((const float4*)((const char*)wsv + 6144))[col];

    // ---- stage this block's 128 rows into LDS (coalesced) ----
    {
        const float4* hg = (const float4*)prev_h;
        #pragma unroll
        for (int i = 0; i < 8; ++i) {
            const int fi = i * 64 + lane;               // 0..511
            const int r = fi >> 2, w = fi & 3;
            const int gi = EXACT ? (wbase * 4 + fi) : min(wbase * 4 + fi, B * 4 - 1);
            const float4 v = hg[gi];
            *(float4*)&W[r * ROW_DW + 4 + w * 4] = v;
        }
        #pragma unroll
        for (int i = 0; i < 2; ++i) {
            const int rr = i * 64 + lane;
            const int zr = EXACT ? (wbase + rr) : min(wbase + rr, B - 1);
            const float z0 = prev_z[zr * 3 + 0];
            const float z1 = prev_z[zr * 3 + 1];
            const float z2 = prev_z[zr * 3 + 2];
            const float ac = action[zr];
            *(float4*)&W[rr * ROW_DW] = make_float4(z0, z1, z2, ac);
        }
    }
    // single wave per block: ds ordering via lgkmcnt, no barrier needed

    #pragma unroll
    for (int t = 0; t < WPT; ++t) {
        // ---- A fragment (uniform LDS reads; k>=20 lanes hold zeros) ----
        const float* ap = &W[(t * 16 + col) * ROW_DW + kg * 8];
        const float4 z4 = make_float4(0.f, 0.f, 0.f, 0.f);
        const float4 p0 = (kg < 3) ? *(const float4*)ap : z4;
        const float4 p1 = (kg < 2) ? *(const float4*)(ap + 4) : z4;
        const half8 a = pack8(p0, p1);

        f32x4 accR  = {bias.x, bias.x, bias.x, bias.x};
        f32x4 accZ  = {bias.y, bias.y, bias.y, bias.y};
        f32x4 accNi = {bias.z, bias.z, bias.z, bias.z};
        f32x4 accNh = {bias.w, bias.w, bias.w, bias.w};
        f32x4 accHp = {0.f, 0.f, 0.f, 0.f};
        accR  = __builtin_amdgcn_mfma_f32_16x16x32_f16(a, bR,  accR,  0, 0, 0);
        accZ  = __builtin_amdgcn_mfma_f32_16x16x32_f16(a, bZ,  accZ,  0, 0, 0);
        accNi = __builtin_amdgcn_mfma_f32_16x16x32_f16(a, bNi, accNi, 0, 0, 0);
        accNh = __builtin_amdgcn_mfma_f32_16x16x32_f16(a, bNh, accNh, 0, 0, 0);
        accHp = __builtin_amdgcn_mfma_f32_16x16x32_f16(a, bHp, accHp, 0, 0, 0);

        // ---- gates (exp2-folded); write hn back into the LDS h-slot ----
        #pragma unroll
        for (int q = 0; q < 4; ++q) {
            const float r  = __builtin_amdgcn_rcpf(1.0f + __builtin_amdgcn_exp2f(accR[q]));
            const float z  = __builtin_amdgcn_rcpf(1.0f + __builtin_amdgcn_exp2f(accZ[q]));
            const float ta = fmaf(r, accNh[q], accNi[q]);            // -2*log2e * y
            const float n  = fmaf(2.0f,
                                  __builtin_amdgcn_rcpf(1.0f + __builtin_amdgcn_exp2f(ta)),
                                  -1.0f);                             // tanh(y)
            const float hv = fmaf(z, accHp[q] - n, n);                // (1-z)*n + z*h
            W[(t * 16 + kg * 4 + q) * ROW_DW + 4 + col] = hv;
        }

        // ---- head MFMA: B2[k][n=col] = hn[col][k] ----
        half8 b2;
        if (kg < 2) {
            const float* hr = &W[(t * 16 + col) * ROW_DW + 4 + kg * 8];
            b2 = pack8(*(const float4*)hr, *(const float4*)(hr + 4));
        } else {
            #pragma unroll
            for (int i = 0; i < 8; ++i) b2[i] = (_Float16)0.f;
            if (kg == 2) b2[4] = (_Float16)1.0f;         // k=20 bias slot
        }
        f32x4 acc2 = {0.f, 0.f, 0.f, 0.f};
        acc2 = __builtin_amdgcn_mfma_f32_16x16x32_f16(a2, b2, acc2, 0, 0, 0);

        // mu/lv into LDS (clamped), packed [row][3] per stream
        const int mr = (t * 16 + col) * 3;
        if (kg == 0) {
            MU[mr + 0] = acc2[0];
            MU[mr + 1] = acc2[1];
            MU[mr + 2] = acc2[2];
            LV[mr + 0] = fminf(fmaxf(acc2[3], -5.0f), 5.0f);
        } else if (kg == 1) {
            LV[mr + 1] = fminf(fmaxf(acc2[0], -5.0f), 5.0f);
            LV[mr + 2] = fminf(fmaxf(acc2[1], -5.0f), 5.0f);
        }

        // ---- cooperative out_h store (nontemporal) ----
        {
            const int r = lane >> 2, w = lane & 3;
            const float4 hv4 = *(const float4*)&W[(t * 16 + r) * ROW_DW + 4 + w * 4];
            const int orow = wbase + t * 16 + r;
            if (EXACT || orow < B)
                nt_store4(&out_h[(size_t)orow * 16 + w * 4], hv4);
        }
    }

    // ---- cooperative mu / lv stores (nontemporal, 1536 B contiguous each) ----
    #pragma unroll
    for (int i = 0; i < 2; ++i) {
        const int sl = i * 48 + ((lane < 48) ? lane : -1);
        if (lane < 48) {
            const int gi = wbase * 3 + (i * 48 + lane) * 4;
            if (EXACT || gi + 3 < B * 3) {
                nt_store4(&out_mu[gi], *(const float4*)&MU[(i * 48 + lane) * 4]);
                nt_store4(&out_lv[gi], *(const float4*)&LV[(i * 48 + lane) * 4]);
            }
        }
        (void)sl;
    }
}

extern "C" void kernel_launch(void* const* d_in, const int* in_sizes, int n_in,
                              void* d_out, int out_size, void* d_ws, size_t ws_size,
                              hipStream_t stream) {
    const float* prev_z = (const float*)d_in[0];
    const float* action = (const float*)d_in[1];
    const float* prev_h = (const float*)d_in[2];
    const float* W_ih   = (const float*)d_in[3];
    const float* W_hh   = (const float*)d_in[4];
    const float* b_ih   = (const float*)d_in[5];
    const float* b_hh   = (const float*)d_in[6];
    const float* W_mu   = (const float*)d_in[7];
    const float* b_mu   = (const float*)d_in[8];
    const float* W_lv   = (const float*)d_in[9];
    const float* b_lv   = (const float*)d_in[10];

    const int B = in_sizes[0] / 3;
    float* out    = (float*)d_out;
    float* out_mu = out;
    float* out_lv = out + (size_t)3 * B;
    float* out_h  = out + (size_t)6 * B;

    prep_kernel<<<1, 64, 0, stream>>>(W_ih, W_hh, b_ih, b_hh,
                                      W_mu, b_mu, W_lv, b_lv, d_ws);

    const int blocks = (B + NROWS - 1) / NROWS;
    if ((B % NROWS) == 0)
        rssm_kernel<true><<<blocks, TPB, 0, stream>>>(prev_z, action, prev_h, d_ws,
                                                      out_mu, out_lv, out_h, B);
    else
        rssm_kernel<false><<<blocks, TPB, 0, stream>>>(prev_z, action, prev_h, d_ws,
                                                       out_mu, out_lv, out_h, B);
}

// Round 19
// 41.509 us; speedup vs baseline: 1.0667x; 1.0667x over previous
//
#include <hip/hip_runtime.h>

#define TPB 64
#define LOG2E 1.44269504088896340736f

typedef _Float16 half8 __attribute__((ext_vector_type(8)));
typedef _Float16 half4 __attribute__((ext_vector_type(4)));
typedef __fp16  fp16x2 __attribute__((ext_vector_type(2)));
typedef float f32x4 __attribute__((ext_vector_type(4)));

__device__ __forceinline__ half8 pack8(float4 lo, float4 hi) {
    union { fp16x2 p[4]; half8 h; } u;
    u.p[0] = __builtin_amdgcn_cvt_pkrtz(lo.x, lo.y);
    u.p[1] = __builtin_amdgcn_cvt_pkrtz(lo.z, lo.w);
    u.p[2] = __builtin_amdgcn_cvt_pkrtz(hi.x, hi.y);
    u.p[3] = __builtin_amdgcn_cvt_pkrtz(hi.z, hi.w);
    return u.h;
}
__device__ __forceinline__ half4 cvt4(float4 v) {
    union { fp16x2 p[2]; half4 h; } u;
    u.p[0] = __builtin_amdgcn_cvt_pkrtz(v.x, v.y);
    u.p[1] = __builtin_amdgcn_cvt_pkrtz(v.z, v.w);
    return u.h;
}
__device__ __forceinline__ half8 cat8(half4 a, half4 b) {
    union { half4 q[2]; half8 o; } u;
    u.q[0] = a; u.q[1] = b;
    return u.o;
}
__device__ __forceinline__ void nt_store4(float* p, float4 v) {
    union { float4 s; f32x4 e; } u;
    u.s = v;
    __builtin_nontemporal_store(u.e, (f32x4*)p);
}

// ---- ws layout (R15 h-first k-map) ----
// halfs: 6 tiles x 512 (r, z, n_i, n_h, hp-identity, A2) = 6144 B
// byte 6144: float4 bias[16] {b_r, b_z, b_ni, b_nh} (exp2-prescaled)
// MAIN k-map: k0-15 = h[0..15], k16-19 = xa(z0,z1,z2,act), k20-31 = 0
// hp identity: B[k][n] = (k==n), k<16. A2: k0-15 = W rows, k20 = bias slot.

__global__ __launch_bounds__(64) void prep_kernel(
    const float* __restrict__ W_ih, const float* __restrict__ W_hh,
    const float* __restrict__ b_ih, const float* __restrict__ b_hh,
    const float* __restrict__ W_mu, const float* __restrict__ b_mu,
    const float* __restrict__ W_lv, const float* __restrict__ b_lv,
    void* __restrict__ wsv)
{
    _Float16* wsB = (_Float16*)wsv;
    const int l = threadIdx.x;
    const int col = l & 15, kg = l >> 4;

    #pragma unroll
    for (int t = 0; t < 4; ++t) {
        const int gate = (t == 0) ? col : (t == 1) ? (16 + col) : (32 + col);
        const float scale = (t <= 1) ? -LOG2E : -2.0f * LOG2E;
        #pragma unroll
        for (int i = 0; i < 8; ++i) {
            const int k = kg * 8 + i;
            float v = 0.f;
            if (t <= 1) {
                if (k < 16)            v = W_hh[gate * 16 + k];
                else if (k < 20)       v = W_ih[gate * 4 + (k - 16)];
            } else if (t == 2) {
                if (k >= 16 && k < 20) v = W_ih[gate * 4 + (k - 16)];
            } else {
                if (k < 16)            v = W_hh[gate * 16 + k];
            }
            wsB[t * 512 + l * 8 + i] = (_Float16)(v * scale);
        }
    }
    #pragma unroll
    for (int i = 0; i < 8; ++i) {
        const int k = kg * 8 + i;
        wsB[4 * 512 + l * 8 + i] = (_Float16)((k == col) ? 1.f : 0.f);
    }
    #pragma unroll
    for (int i = 0; i < 8; ++i) {
        const int k = kg * 8 + i;
        const int m = col;
        float v = 0.f;
        if (m < 3) {
            if (k < 16)       v = W_mu[m * 16 + k];
            else if (k == 20) v = b_mu[m];
        } else if (m < 6) {
            if (k < 16)       v = W_lv[(m - 3) * 16 + k];
            else if (k == 20) v = b_lv[m - 3];
        }
        wsB[5 * 512 + l * 8 + i] = (_Float16)v;
    }
    if (l < 16) {
        float4* b4 = (float4*)((char*)wsv + 6144);
        b4[l] = make_float4(-LOG2E * (b_ih[l] + b_hh[l]),
                            -LOG2E * (b_ih[16 + l] + b_hh[16 + l]),
                            -2.0f * LOG2E * b_ih[32 + l],
                            -2.0f * LOG2E * b_hh[32 + l]);
    }
}

template<bool EXACT>
__global__ __launch_bounds__(TPB, 4) void rssm_kernel(
    const float* __restrict__ prev_z,   // [B,3]
    const float* __restrict__ action,   // [B,1]
    const float* __restrict__ prev_h,   // [B,16]
    const void*  __restrict__ wsv,
    float* __restrict__ out_mu,         // [B,3]
    float* __restrict__ out_lv,         // [B,3]
    float* __restrict__ out_h,          // [B,16]
    int B)
{
    __shared__ __align__(16) float Hb[2][64 * 16];   // dense h rows, 4 KB/chunk
    __shared__ __align__(8)  _Float16 XAb[64 * 4];   // per-chunk xa (reused)
    __shared__ float MU[192], LV[192];

    const int lane = threadIdx.x;
    const int col = lane & 15, kg = lane >> 4;
    const int bbase = blockIdx.x * 128;              // 2 chunks of 64 rows
    if (!EXACT && bbase >= B) return;

    // ---- wave-invariant fragments ----
    const half8* Bp = (const half8*)wsv;
    const half8 bR  = Bp[lane];
    const half8 bZ  = Bp[64 + lane];
    const half8 bNi = Bp[128 + lane];
    const half8 bNh = Bp[192 + lane];
    const half8 bHp = Bp[256 + lane];
    const half8 a2  = Bp[320 + lane];
    const float4 bias = ((const float4*)((const char*)wsv + 6144))[col];

    // ---- stage BOTH chunks' h via async global->LDS (no VGPR cost) ----
    if constexpr (EXACT) {
        const float4* hg = (const float4*)(prev_h + (size_t)bbase * 16);
        #pragma unroll
        for (int c = 0; c < 2; ++c)
            #pragma unroll
            for (int i = 0; i < 4; ++i)
                __builtin_amdgcn_global_load_lds(
                    (const void*)(hg + c * 256 + i * 64 + lane),
                    (void*)&Hb[c][i * 256], 16, 0, 0);
        // wait for chunk 0's 4 glls only; chunk 1 stays in flight.
        // (any compiler-hoisted vmem only ADDS newer ops -> over-wait, safe)
        asm volatile("s_waitcnt vmcnt(4)" ::: "memory");
        __builtin_amdgcn_sched_barrier(0);
    } else {
        const float4* hg = (const float4*)prev_h;
        #pragma unroll
        for (int c = 0; c < 2; ++c)
            #pragma unroll
            for (int i = 0; i < 4; ++i) {
                const int gi = min(bbase * 4 + c * 256 + i * 64 + lane, B * 4 - 1);
                *(float4*)&Hb[c][i * 256 + lane * 4] = hg[gi];
            }
    }

    half4 zz; zz[0] = zz[1] = zz[2] = zz[3] = (_Float16)0.f;

    #pragma unroll
    for (int c = 0; c < 2; ++c) {
        const int cbase = bbase + c * 64;
        if (EXACT || cbase < B) {
            if (EXACT && c == 1) {
                asm volatile("s_waitcnt vmcnt(0)" ::: "memory");
                __builtin_amdgcn_sched_barrier(0);
            }
            float* Hc = Hb[c];

            // ---- xa stage for this chunk (512 B, same-wave lgkm ordering) ----
            {
                const int zr = EXACT ? (cbase + lane) : min(cbase + lane, B - 1);
                *(half4*)&XAb[lane * 4] =
                    cvt4(make_float4(prev_z[zr * 3 + 0], prev_z[zr * 3 + 1],
                                     prev_z[zr * 3 + 2], action[zr]));
            }

            #pragma unroll
            for (int t = 0; t < 4; ++t) {
                // ---- A fragment: h from dense LDS rows, xa from XAb ----
                half8 a;
                if (kg < 2) {
                    const float4 p0 = *(const float4*)&Hc[(t * 16 + col) * 16 + kg * 8];
                    const float4 p1 = *(const float4*)&Hc[(t * 16 + col) * 16 + kg * 8 + 4];
                    a = pack8(p0, p1);
                } else if (kg == 2) {
                    a = cat8(*(const half4*)&XAb[(t * 16 + col) * 4], zz);
                } else {
                    a = cat8(zz, zz);
                }

                f32x4 accR  = {bias.x, bias.x, bias.x, bias.x};
                f32x4 accZ  = {bias.y, bias.y, bias.y, bias.y};
                f32x4 accNi = {bias.z, bias.z, bias.z, bias.z};
                f32x4 accNh = {bias.w, bias.w, bias.w, bias.w};
                f32x4 accHp = {0.f, 0.f, 0.f, 0.f};
                accR  = __builtin_amdgcn_mfma_f32_16x16x32_f16(a, bR,  accR,  0, 0, 0);
                accZ  = __builtin_amdgcn_mfma_f32_16x16x32_f16(a, bZ,  accZ,  0, 0, 0);
                accNi = __builtin_amdgcn_mfma_f32_16x16x32_f16(a, bNi, accNi, 0, 0, 0);
                accNh = __builtin_amdgcn_mfma_f32_16x16x32_f16(a, bNh, accNh, 0, 0, 0);
                accHp = __builtin_amdgcn_mfma_f32_16x16x32_f16(a, bHp, accHp, 0, 0, 0);

                // ---- gates (exp2-folded); hn overwrites the h slot ----
                #pragma unroll
                for (int q = 0; q < 4; ++q) {
                    const float r  = __builtin_amdgcn_rcpf(1.0f + __builtin_amdgcn_exp2f(accR[q]));
                    const float z  = __builtin_amdgcn_rcpf(1.0f + __builtin_amdgcn_exp2f(accZ[q]));
                    const float ta = fmaf(r, accNh[q], accNi[q]);
                    const float n  = fmaf(2.0f,
                                          __builtin_amdgcn_rcpf(1.0f + __builtin_amdgcn_exp2f(ta)),
                                          -1.0f);
                    const float hv = fmaf(z, accHp[q] - n, n);       // (1-z)*n + z*h
                    Hc[(t * 16 + kg * 4 + q) * 16 + col] = hv;
                }

                // ---- head MFMA: B2[k][n=col] = hn[col][k] ----
                half8 b2;
                if (kg < 2) {
                    const float4 h0 = *(const float4*)&Hc[(t * 16 + col) * 16 + kg * 8];
                    const float4 h1 = *(const float4*)&Hc[(t * 16 + col) * 16 + kg * 8 + 4];
                    b2 = pack8(h0, h1);
                } else {
                    b2 = cat8(zz, zz);
                    if (kg == 2) b2[4] = (_Float16)1.0f;             // k=20 bias slot
                }
                f32x4 acc2 = {0.f, 0.f, 0.f, 0.f};
                acc2 = __builtin_amdgcn_mfma_f32_16x16x32_f16(a2, b2, acc2, 0, 0, 0);

                const int mr = (t * 16 + col) * 3;
                if (kg == 0) {
                    MU[mr + 0] = acc2[0];
                    MU[mr + 1] = acc2[1];
                    MU[mr + 2] = acc2[2];
                    LV[mr + 0] = fminf(fmaxf(acc2[3], -5.0f), 5.0f);
                } else if (kg == 1) {
                    LV[mr + 1] = fminf(fmaxf(acc2[0], -5.0f), 5.0f);
                    LV[mr + 2] = fminf(fmaxf(acc2[1], -5.0f), 5.0f);
                }

                // ---- cooperative out_h store (nontemporal) ----
                {
                    const int r = lane >> 2, w = lane & 3;
                    const float4 hv4 = *(const float4*)&Hc[(t * 16 + r) * 16 + w * 4];
                    const int orow = cbase + t * 16 + r;
                    if (EXACT || orow < B)
                        nt_store4(&out_h[(size_t)orow * 16 + w * 4], hv4);
                }
            }

            // ---- cooperative mu / lv stores (nontemporal) ----
            if (lane < 48) {
                const int gi = cbase * 3 + lane * 4;
                if (EXACT || gi + 3 < B * 3) {
                    nt_store4(&out_mu[gi], *(const float4*)&MU[lane * 4]);
                    nt_store4(&out_lv[gi], *(const float4*)&LV[lane * 4]);
                }
            }
        }
    }
}

extern "C" void kernel_launch(void* const* d_in, const int* in_sizes, int n_in,
                              void* d_out, int out_size, void* d_ws, size_t ws_size,
                              hipStream_t stream) {
    const float* prev_z = (const float*)d_in[0];
    const float* action = (const float*)d_in[1];
    const float* prev_h = (const float*)d_in[2];
    const float* W_ih   = (const float*)d_in[3];
    const float* W_hh   = (const float*)d_in[4];
    const float* b_ih   = (const float*)d_in[5];
    const float* b_hh   = (const float*)d_in[6];
    const float* W_mu   = (const float*)d_in[7];
    const float* b_mu   = (const float*)d_in[8];
    const float* W_lv   = (const float*)d_in[9];
    const float* b_lv   = (const float*)d_in[10];

    const int B = in_sizes[0] / 3;
    float* out    = (float*)d_out;
    float* out_mu = out;
    float* out_lv = out + (size_t)3 * B;
    float* out_h  = out + (size_t)6 * B;

    prep_kernel<<<1, 64, 0, stream>>>(W_ih, W_hh, b_ih, b_hh,
                                      W_mu, b_mu, W_lv, b_lv, d_ws);

    const int rows_per_block = 128;
    const int blocks = (B + rows_per_block - 1) / rows_per_block;
    if ((B % rows_per_block) == 0)
        rssm_kernel<true><<<blocks, TPB, 0, stream>>>(prev_z, action, prev_h, d_ws,
                                                      out_mu, out_lv, out_h, B);
    else
        rssm_kernel<false><<<blocks, TPB, 0, stream>>>(prev_z, action, prev_h, d_ws,
                                                       out_mu, out_lv, out_h, B);
}